// Round 13
// baseline (28.341 us; speedup 1.0000x reference)
//
#include <hip/hip_runtime.h>

#define NF 39
#define NE 40
#define NB 4096
#define NP 741
#define NDW 384               // dense u32 words per sample (768 bf16, 741 valid + 27 zero pad)
#define NSLOT 1536            // 6 tiles * 256 MFMA slots (stats space)
#define NBLK 512
#define SPW 2                 // samples per wave
#define SPB 8                 // samples per block (4 waves * SPW)
#define K2_BLOCKS 48          // 48 * 32 slots = 1536
#define EPS 1.0e-3f

typedef __attribute__((ext_vector_type(8))) short short8;
typedef __attribute__((ext_vector_type(4))) float floatx4;

__device__ __forceinline__ unsigned int f2bf(float f) {
    unsigned int b = __float_as_uint(f);
    b += 0x7FFFu + ((b >> 16) & 1u);   // round-to-nearest-even
    return b >> 16;
}

__device__ __forceinline__ float bf2f(unsigned int u) {
    return __uint_as_float(u << 16);
}

__device__ __forceinline__ short8 pack8(float4 a, float4 b) {
    union { unsigned int u[4]; short8 s; } o;
    o.u[0] = f2bf(a.x) | (f2bf(a.y) << 16);
    o.u[1] = f2bf(a.z) | (f2bf(a.w) << 16);
    o.u[2] = f2bf(b.x) | (f2bf(b.y) << 16);
    o.u[3] = f2bf(b.z) | (f2bf(b.w) << 16);
    return o.s;
}

// Direct-to-register fragment gather for one sample (validated R4-R12).
__device__ __forceinline__ void load_frags(
    const int* __restrict__ ip, const float* __restrict__ v,
    int rbase, int ehalf, short8 F0[3], short8 F1[3])
{
    const float4 zero4 = {0.f, 0.f, 0.f, 0.f};
#pragma unroll
    for (int I = 0; I < 3; ++I) {
        const int r = rbase + 16 * I;
        const bool vr = (r < NF);
        const int id = vr ? ip[r] : 0;
        const float* vrow = v + (size_t)id * NE;
        const float4 a  = vr ? *reinterpret_cast<const float4*>(vrow + ehalf * 8)     : zero4;
        const float4 bq = vr ? *reinterpret_cast<const float4*>(vrow + ehalf * 8 + 4) : zero4;
        F0[I] = pack8(a, bq);
        const bool v1 = vr && (ehalf == 0);
        const float4 c_ = v1 ? *reinterpret_cast<const float4*>(vrow + 32) : zero4;
        const float4 d_ = v1 ? *reinterpret_cast<const float4*>(vrow + 36) : zero4;
        F1[I] = pack8(c_, d_);
    }
}

__device__ __forceinline__ void gram_mfma(const short8 F0[3], const short8 F1[3], floatx4 acc[6])
{
    acc[0] = __builtin_amdgcn_mfma_f32_16x16x32_bf16(F0[0], F0[0], acc[0], 0, 0, 0);
    acc[1] = __builtin_amdgcn_mfma_f32_16x16x32_bf16(F0[0], F0[1], acc[1], 0, 0, 0);
    acc[2] = __builtin_amdgcn_mfma_f32_16x16x32_bf16(F0[0], F0[2], acc[2], 0, 0, 0);
    acc[3] = __builtin_amdgcn_mfma_f32_16x16x32_bf16(F0[1], F0[1], acc[3], 0, 0, 0);
    acc[4] = __builtin_amdgcn_mfma_f32_16x16x32_bf16(F0[1], F0[2], acc[4], 0, 0, 0);
    acc[5] = __builtin_amdgcn_mfma_f32_16x16x32_bf16(F0[2], F0[2], acc[5], 0, 0, 0);
    acc[0] = __builtin_amdgcn_mfma_f32_16x16x32_bf16(F1[0], F1[0], acc[0], 0, 0, 0);
    acc[1] = __builtin_amdgcn_mfma_f32_16x16x32_bf16(F1[0], F1[1], acc[1], 0, 0, 0);
    acc[2] = __builtin_amdgcn_mfma_f32_16x16x32_bf16(F1[0], F1[2], acc[2], 0, 0, 0);
    acc[3] = __builtin_amdgcn_mfma_f32_16x16x32_bf16(F1[1], F1[1], acc[3], 0, 0, 0);
    acc[4] = __builtin_amdgcn_mfma_f32_16x16x32_bf16(F1[1], F1[2], acc[4], 0, 0, 0);
    acc[5] = __builtin_amdgcn_mfma_f32_16x16x32_bf16(F1[2], F1[2], acc[5], 0, 0, 0);
}

// ---------------- Kernel 1: gather + Gram -> dense bf16 G (LDS compaction) + stats fold + lsum ----------------
__global__ __launch_bounds__(256) void fm_k1(
    const int* __restrict__ inputs, const float* __restrict__ w,
    const float* __restrict__ v, unsigned int* __restrict__ Gd,
    float* __restrict__ lsum, unsigned int* __restrict__ partial)
{
    __shared__ union {
        unsigned short dense[4][2 * NDW];   // 6 KB transient per-wave compaction rows
        float red[4 * 2 * NSLOT];           // 48 KB cross-wave stats fold
    } sm;
    const int t = threadIdx.x, wid = t >> 6, lane = t & 63;
    const int rbase = lane & 15, ehalf = lane >> 4;
    const int b0 = blockIdx.x * SPB;
    const int TI[6] = {0, 0, 0, 1, 1, 2};
    const int TJ[6] = {0, 1, 2, 1, 2, 2};

    floatx4 sum[6] = {}, sq[6] = {};
#pragma unroll
    for (int s = 0; s < SPW; ++s) {
        const int smp = b0 + wid * SPW + s;
        const int* ip = inputs + (size_t)smp * NF;
        short8 F0[3], F1[3];
        load_frags(ip, v, rbase, ehalf, F0, F1);

        // first-order term
        float wv = (lane < NF) ? w[ip[lane]] : 0.0f;
#pragma unroll
        for (int o = 32; o > 0; o >>= 1) wv += __shfl_down(wv, o, 64);
        if (lane == 0) lsum[smp] = wv;

        floatx4 acc[6] = {};
        gram_mfma(F0, F1, acc);
#pragma unroll
        for (int tl = 0; tl < 6; ++tl) {
            sum[tl] += acc[tl];
            sq[tl]  += acc[tl] * acc[tl];
        }

        // LDS compaction: scatter valid slots to dense pair index p
        unsigned short* dw = sm.dense[wid];
        if (lane < 2 * NDW - NP) dw[NP + lane] = 0;   // zero 27-halfword pad
#pragma unroll
        for (int tl = 0; tl < 6; ++tl)
#pragma unroll
            for (int q = 0; q < 4; ++q) {
                const int gi = 16 * TI[tl] + 4 * ehalf + q;
                const int gj = 16 * TJ[tl] + rbase;
                if (gi < gj && gj < NF) {
                    const int p = 38 * gi - (gi * (gi - 1)) / 2 + (gj - gi - 1);
                    dw[p] = (unsigned short)f2bf(acc[tl][q]);
                }
            }
        __syncthreads();
        // coalesced dense store (24 B/lane)
        const unsigned int* dwu = reinterpret_cast<const unsigned int*>(dw);
        unsigned int* go = Gd + (size_t)smp * NDW;
#pragma unroll
        for (int k = 0; k < 6; ++k) go[lane + 64 * k] = dwu[lane + 64 * k];
        __syncthreads();   // WAR: LDS reused next sample / by fold
    }

    // stats fold (slot space, R12-proven) + bf16-packed partial
    float* rw = &sm.red[wid * 2 * NSLOT];
#pragma unroll
    for (int tl = 0; tl < 6; ++tl) {
        *reinterpret_cast<floatx4*>(rw + tl * 256 + lane * 4)         = sum[tl];
        *reinterpret_cast<floatx4*>(rw + NSLOT + tl * 256 + lane * 4) = sq[tl];
    }
    __syncthreads();
    unsigned int* po = partial + (size_t)blockIdx.x * NSLOT;
    for (int j = t; j < NSLOT; j += 256) {
        const float s = sm.red[j] + sm.red[2 * NSLOT + j] + sm.red[4 * NSLOT + j] + sm.red[6 * NSLOT + j];
        const float q = sm.red[NSLOT + j] + sm.red[3 * NSLOT + j] + sm.red[5 * NSLOT + j] + sm.red[7 * NSLOT + j];
        po[j] = (f2bf(s) << 16) | f2bf(q);
    }
}

// ---------------- Kernel 2: column-reduce + finalize -> dense-order mean/scale ----------------
__global__ __launch_bounds__(256) void fm_k2(
    const unsigned int* __restrict__ partial, const float* __restrict__ ew,
    float* __restrict__ meanD, float* __restrict__ scaleD)
{
    const int t = threadIdx.x;
    const int slotL = t & 31, rg = t >> 5;          // 8 row-groups x 64 rows
    const int slot0 = blockIdx.x * 32;
    // zero dense pads (avoid NaN poison downstream)
    if (blockIdx.x == 0 && t >= 64 && t < 64 + (2 * NDW - NP)) {
        meanD[NP + t - 64]  = 0.0f;
        scaleD[NP + t - 64] = 0.0f;
    }
    float s1 = 0.f, s2 = 0.f;
#pragma unroll 8
    for (int r = 0; r < 64; ++r) {
        const unsigned int u = partial[(size_t)(rg * 64 + r) * NSLOT + slot0 + slotL];
        s1 += __uint_as_float(u & 0xFFFF0000u);   // sum (high half)
        s2 += __uint_as_float(u << 16);           // sumsq (low half)
    }
    __shared__ float r1[8][32], r2[8][32];
    r1[rg][slotL] = s1;
    r2[rg][slotL] = s2;
    __syncthreads();
    if (t < 32) {
        float a = 0.f, b = 0.f;
#pragma unroll
        for (int g = 0; g < 8; ++g) { a += r1[g][t]; b += r2[g][t]; }
        const int slot = slot0 + t;
        const float m   = a * (1.0f / NB);
        const float var = b * (1.0f / NB) - m * m;
        const int tile = slot >> 8;
        const int l    = (slot & 255) >> 2;
        const int q    = slot & 3;
        const int TI[6] = {0, 0, 0, 1, 1, 2};
        const int TJ[6] = {0, 1, 2, 1, 2, 2};
        const int gi = 16 * TI[tile] + ((l >> 4) << 2) + q;
        const int gj = 16 * TJ[tile] + (l & 15);
        if (gi < gj && gj < NF) {
            const int p = 38 * gi - (gi * (gi - 1)) / 2 + (gj - gi - 1);
            meanD[p]  = m;
            scaleD[p] = ew[p] * rsqrtf(var + EPS);
        }
    }
}

// ---------------- Kernel 3: stream dense bf16 G + normalize-reduce + first-order ----------------
__global__ __launch_bounds__(256) void fm_k3(
    const unsigned int* __restrict__ Gd, const float* __restrict__ lsum,
    const float* __restrict__ meanD, const float* __restrict__ scaleD,
    const float* __restrict__ bias, float* __restrict__ out)
{
    const int t = threadIdx.x, wid = t >> 6, lane = t & 63;
    const int b0 = blockIdx.x * SPB;

    float2 mf[6], sf[6];
#pragma unroll
    for (int k = 0; k < 6; ++k) {
        mf[k] = *reinterpret_cast<const float2*>(meanD  + 2 * (lane + 64 * k));
        sf[k] = *reinterpret_cast<const float2*>(scaleD + 2 * (lane + 64 * k));
    }
    const float bs = bias[0];

#pragma unroll
    for (int s = 0; s < SPW; ++s) {
        const int smp = b0 + wid * SPW + s;
        const unsigned int* gr = Gd + (size_t)smp * NDW;
        float tot = (lane == 0) ? lsum[smp] : 0.0f;
#pragma unroll
        for (int k = 0; k < 6; ++k) {
            const unsigned int u = gr[lane + 64 * k];
            tot += (bf2f(u & 0xFFFFu) - mf[k].x) * sf[k].x;
            tot += (bf2f(u >> 16)     - mf[k].y) * sf[k].y;
        }
#pragma unroll
        for (int o = 32; o > 0; o >>= 1) tot += __shfl_down(tot, o, 64);
        if (lane == 0) out[smp] = tot + bs;
    }
}

extern "C" void kernel_launch(void* const* d_in, const int* in_sizes, int n_in,
                              void* d_out, int out_size, void* d_ws, size_t ws_size,
                              hipStream_t stream)
{
    const int*   inputs = (const int*)  d_in[0];
    // d_in[1]=rows, d_in[2]=cols reproduced in-kernel (validated R2-R12)
    const float* w      = (const float*)d_in[3];
    const float* v      = (const float*)d_in[4];
    const float* bias   = (const float*)d_in[5];
    const float* ew     = (const float*)d_in[6];
    float*       out    = (float*)      d_out;

    // ws: Gd u32[4096*384] | partial u32[512*1536] | meanD f32[768] | scaleD f32[768] | lsum f32[4096]
    unsigned int* Gd      = (unsigned int*)d_ws;
    unsigned int* partial = Gd + (size_t)NB * NDW;
    float* meanD  = (float*)(partial + (size_t)NBLK * NSLOT);
    float* scaleD = meanD + 2 * NDW;
    float* lsum   = scaleD + 2 * NDW;

    fm_k1<<<NBLK,      256, 0, stream>>>(inputs, w, v, Gd, lsum, partial);
    fm_k2<<<K2_BLOCKS, 256, 0, stream>>>(partial, ew, meanD, scaleD);
    fm_k3<<<NBLK,      256, 0, stream>>>(Gd, lsum, meanD, scaleD, bias, out);
}

// Round 14
// 28.221 us; speedup vs baseline: 1.0043x; 1.0043x over previous
//
#include <hip/hip_runtime.h>

#define NF 39
#define NE 40
#define NB 4096
#define NP 741
#define NDW 384               // dense u32 words per sample (768 bf16, 741 valid + 27 zero pad)
#define NSLOT 1536            // 6 tiles * 256 MFMA slots (stats space)
#define NBLK 512
#define SPW 2                 // samples per wave
#define SPB 8                 // samples per block (4 waves * SPW)
#define K2_BLOCKS 48          // 48 * 32 slots = 1536
#define EPS 1.0e-3f

typedef __attribute__((ext_vector_type(8))) short short8;
typedef __attribute__((ext_vector_type(4))) float floatx4;

__device__ __forceinline__ unsigned int f2bf(float f) {
    unsigned int b = __float_as_uint(f);
    b += 0x7FFFu + ((b >> 16) & 1u);   // round-to-nearest-even
    return b >> 16;
}

__device__ __forceinline__ float bf2f(unsigned int u) {
    return __uint_as_float(u << 16);
}

__device__ __forceinline__ short8 pack8(float4 a, float4 b) {
    union { unsigned int u[4]; short8 s; } o;
    o.u[0] = f2bf(a.x) | (f2bf(a.y) << 16);
    o.u[1] = f2bf(a.z) | (f2bf(a.w) << 16);
    o.u[2] = f2bf(b.x) | (f2bf(b.y) << 16);
    o.u[3] = f2bf(b.z) | (f2bf(b.w) << 16);
    return o.s;
}

// Direct-to-register fragment gather for one sample (validated R4-R13).
__device__ __forceinline__ void load_frags(
    const int* __restrict__ ip, const float* __restrict__ v,
    int rbase, int ehalf, short8 F0[3], short8 F1[3])
{
    const float4 zero4 = {0.f, 0.f, 0.f, 0.f};
#pragma unroll
    for (int I = 0; I < 3; ++I) {
        const int r = rbase + 16 * I;
        const bool vr = (r < NF);
        const int id = vr ? ip[r] : 0;
        const float* vrow = v + (size_t)id * NE;
        const float4 a  = vr ? *reinterpret_cast<const float4*>(vrow + ehalf * 8)     : zero4;
        const float4 bq = vr ? *reinterpret_cast<const float4*>(vrow + ehalf * 8 + 4) : zero4;
        F0[I] = pack8(a, bq);
        const bool v1 = vr && (ehalf == 0);
        const float4 c_ = v1 ? *reinterpret_cast<const float4*>(vrow + 32) : zero4;
        const float4 d_ = v1 ? *reinterpret_cast<const float4*>(vrow + 36) : zero4;
        F1[I] = pack8(c_, d_);
    }
}

__device__ __forceinline__ void gram_mfma(const short8 F0[3], const short8 F1[3], floatx4 acc[6])
{
    acc[0] = __builtin_amdgcn_mfma_f32_16x16x32_bf16(F0[0], F0[0], acc[0], 0, 0, 0);
    acc[1] = __builtin_amdgcn_mfma_f32_16x16x32_bf16(F0[0], F0[1], acc[1], 0, 0, 0);
    acc[2] = __builtin_amdgcn_mfma_f32_16x16x32_bf16(F0[0], F0[2], acc[2], 0, 0, 0);
    acc[3] = __builtin_amdgcn_mfma_f32_16x16x32_bf16(F0[1], F0[1], acc[3], 0, 0, 0);
    acc[4] = __builtin_amdgcn_mfma_f32_16x16x32_bf16(F0[1], F0[2], acc[4], 0, 0, 0);
    acc[5] = __builtin_amdgcn_mfma_f32_16x16x32_bf16(F0[2], F0[2], acc[5], 0, 0, 0);
    acc[0] = __builtin_amdgcn_mfma_f32_16x16x32_bf16(F1[0], F1[0], acc[0], 0, 0, 0);
    acc[1] = __builtin_amdgcn_mfma_f32_16x16x32_bf16(F1[0], F1[1], acc[1], 0, 0, 0);
    acc[2] = __builtin_amdgcn_mfma_f32_16x16x32_bf16(F1[0], F1[2], acc[2], 0, 0, 0);
    acc[3] = __builtin_amdgcn_mfma_f32_16x16x32_bf16(F1[1], F1[1], acc[3], 0, 0, 0);
    acc[4] = __builtin_amdgcn_mfma_f32_16x16x32_bf16(F1[1], F1[2], acc[4], 0, 0, 0);
    acc[5] = __builtin_amdgcn_mfma_f32_16x16x32_bf16(F1[2], F1[2], acc[5], 0, 0, 0);
}

// ---------------- Kernel 1: gather + Gram -> dense bf16 G (per-wave LDS compaction, barrier-free) ----------------
__global__ __launch_bounds__(256) void fm_k1(
    const int* __restrict__ inputs, const float* __restrict__ w,
    const float* __restrict__ v, unsigned int* __restrict__ Gd,
    float* __restrict__ lsum, unsigned int* __restrict__ partial)
{
    __shared__ union {
        unsigned short dense[4][2 * NDW];   // 6 KB transient per-WAVE compaction rows
        float red[4 * 2 * NSLOT];           // 48 KB cross-wave stats fold
    } sm;
    const int t = threadIdx.x, wid = t >> 6, lane = t & 63;
    const int rbase = lane & 15, ehalf = lane >> 4;
    const int b0 = blockIdx.x * SPB;
    const int TI[6] = {0, 0, 0, 1, 1, 2};
    const int TJ[6] = {0, 1, 2, 1, 2, 2};

    floatx4 sum[6] = {}, sq[6] = {};
#pragma unroll
    for (int s = 0; s < SPW; ++s) {
        __builtin_amdgcn_wave_barrier();   // pin LDS op ordering across iterations (no exec cost)
        const int smp = b0 + wid * SPW + s;
        const int* ip = inputs + (size_t)smp * NF;
        short8 F0[3], F1[3];
        load_frags(ip, v, rbase, ehalf, F0, F1);

        // first-order term
        float wv = (lane < NF) ? w[ip[lane]] : 0.0f;
#pragma unroll
        for (int o = 32; o > 0; o >>= 1) wv += __shfl_down(wv, o, 64);
        if (lane == 0) lsum[smp] = wv;

        floatx4 acc[6] = {};
        gram_mfma(F0, F1, acc);
#pragma unroll
        for (int tl = 0; tl < 6; ++tl) {
            sum[tl] += acc[tl];
            sq[tl]  += acc[tl] * acc[tl];
        }

        // per-wave LDS compaction: scatter valid slots to dense pair index p
        unsigned short* dw = sm.dense[wid];
        if (lane < 2 * NDW - NP) dw[NP + lane] = 0;   // zero 27-halfword pad
#pragma unroll
        for (int tl = 0; tl < 6; ++tl)
#pragma unroll
            for (int q = 0; q < 4; ++q) {
                const int gi = 16 * TI[tl] + 4 * ehalf + q;
                const int gj = 16 * TJ[tl] + rbase;
                if (gi < gj && gj < NF) {
                    const int p = 38 * gi - (gi * (gi - 1)) / 2 + (gj - gi - 1);
                    dw[p] = (unsigned short)f2bf(acc[tl][q]);
                }
            }
        __builtin_amdgcn_wave_barrier();
        // coalesced dense store (24 B/lane); same-wave DS FIFO ordering guarantees visibility
        const unsigned int* dwu = reinterpret_cast<const unsigned int*>(dw);
        unsigned int* go = Gd + (size_t)smp * NDW;
#pragma unroll
        for (int k = 0; k < 6; ++k) go[lane + 64 * k] = dwu[lane + 64 * k];
    }

    __syncthreads();   // dense rows dead; red overlaps other waves' dense -> one block barrier
    // stats fold (slot space, R12-proven) + bf16-packed partial
    float* rw = &sm.red[wid * 2 * NSLOT];
#pragma unroll
    for (int tl = 0; tl < 6; ++tl) {
        *reinterpret_cast<floatx4*>(rw + tl * 256 + lane * 4)         = sum[tl];
        *reinterpret_cast<floatx4*>(rw + NSLOT + tl * 256 + lane * 4) = sq[tl];
    }
    __syncthreads();
    unsigned int* po = partial + (size_t)blockIdx.x * NSLOT;
    for (int j = t; j < NSLOT; j += 256) {
        const float s = sm.red[j] + sm.red[2 * NSLOT + j] + sm.red[4 * NSLOT + j] + sm.red[6 * NSLOT + j];
        const float q = sm.red[NSLOT + j] + sm.red[3 * NSLOT + j] + sm.red[5 * NSLOT + j] + sm.red[7 * NSLOT + j];
        po[j] = (f2bf(s) << 16) | f2bf(q);
    }
}

// ---------------- Kernel 2: column-reduce + finalize -> dense-order mean/scale ----------------
__global__ __launch_bounds__(256) void fm_k2(
    const unsigned int* __restrict__ partial, const float* __restrict__ ew,
    float* __restrict__ meanD, float* __restrict__ scaleD)
{
    const int t = threadIdx.x;
    const int slotL = t & 31, rg = t >> 5;          // 8 row-groups x 64 rows
    const int slot0 = blockIdx.x * 32;
    // zero dense pads (avoid NaN poison downstream)
    if (blockIdx.x == 0 && t >= 64 && t < 64 + (2 * NDW - NP)) {
        meanD[NP + t - 64]  = 0.0f;
        scaleD[NP + t - 64] = 0.0f;
    }
    float s1 = 0.f, s2 = 0.f;
#pragma unroll 8
    for (int r = 0; r < 64; ++r) {
        const unsigned int u = partial[(size_t)(rg * 64 + r) * NSLOT + slot0 + slotL];
        s1 += __uint_as_float(u & 0xFFFF0000u);   // sum (high half)
        s2 += __uint_as_float(u << 16);           // sumsq (low half)
    }
    __shared__ float r1[8][32], r2[8][32];
    r1[rg][slotL] = s1;
    r2[rg][slotL] = s2;
    __syncthreads();
    if (t < 32) {
        float a = 0.f, b = 0.f;
#pragma unroll
        for (int g = 0; g < 8; ++g) { a += r1[g][t]; b += r2[g][t]; }
        const int slot = slot0 + t;
        const float m   = a * (1.0f / NB);
        const float var = b * (1.0f / NB) - m * m;
        const int tile = slot >> 8;
        const int l    = (slot & 255) >> 2;
        const int q    = slot & 3;
        const int TI[6] = {0, 0, 0, 1, 1, 2};
        const int TJ[6] = {0, 1, 2, 1, 2, 2};
        const int gi = 16 * TI[tile] + ((l >> 4) << 2) + q;
        const int gj = 16 * TJ[tile] + (l & 15);
        if (gi < gj && gj < NF) {
            const int p = 38 * gi - (gi * (gi - 1)) / 2 + (gj - gi - 1);
            meanD[p]  = m;
            scaleD[p] = ew[p] * rsqrtf(var + EPS);
        }
    }
}

// ---------------- Kernel 3: stream dense bf16 G + normalize-reduce + first-order ----------------
__global__ __launch_bounds__(256) void fm_k3(
    const unsigned int* __restrict__ Gd, const float* __restrict__ lsum,
    const float* __restrict__ meanD, const float* __restrict__ scaleD,
    const float* __restrict__ bias, float* __restrict__ out)
{
    const int t = threadIdx.x, wid = t >> 6, lane = t & 63;
    const int b0 = blockIdx.x * SPB;

    float2 mf[6], sf[6];
#pragma unroll
    for (int k = 0; k < 6; ++k) {
        mf[k] = *reinterpret_cast<const float2*>(meanD  + 2 * (lane + 64 * k));
        sf[k] = *reinterpret_cast<const float2*>(scaleD + 2 * (lane + 64 * k));
    }
    const float bs = bias[0];

#pragma unroll
    for (int s = 0; s < SPW; ++s) {
        const int smp = b0 + wid * SPW + s;
        const unsigned int* gr = Gd + (size_t)smp * NDW;
        float tot = (lane == 0) ? lsum[smp] : 0.0f;
#pragma unroll
        for (int k = 0; k < 6; ++k) {
            const unsigned int u = gr[lane + 64 * k];
            tot += (bf2f(u & 0xFFFFu) - mf[k].x) * sf[k].x;
            tot += (bf2f(u >> 16)     - mf[k].y) * sf[k].y;
        }
#pragma unroll
        for (int o = 32; o > 0; o >>= 1) tot += __shfl_down(tot, o, 64);
        if (lane == 0) out[smp] = tot + bs;
    }
}

extern "C" void kernel_launch(void* const* d_in, const int* in_sizes, int n_in,
                              void* d_out, int out_size, void* d_ws, size_t ws_size,
                              hipStream_t stream)
{
    const int*   inputs = (const int*)  d_in[0];
    // d_in[1]=rows, d_in[2]=cols reproduced in-kernel (validated R2-R13)
    const float* w      = (const float*)d_in[3];
    const float* v      = (const float*)d_in[4];
    const float* bias   = (const float*)d_in[5];
    const float* ew     = (const float*)d_in[6];
    float*       out    = (float*)      d_out;

    // ws: Gd u32[4096*384] | partial u32[512*1536] | meanD f32[768] | scaleD f32[768] | lsum f32[4096]
    unsigned int* Gd      = (unsigned int*)d_ws;
    unsigned int* partial = Gd + (size_t)NB * NDW;
    float* meanD  = (float*)(partial + (size_t)NBLK * NSLOT);
    float* scaleD = meanD + 2 * NDW;
    float* lsum   = scaleD + 2 * NDW;

    fm_k1<<<NBLK,      256, 0, stream>>>(inputs, w, v, Gd, lsum, partial);
    fm_k2<<<K2_BLOCKS, 256, 0, stream>>>(partial, ew, meanD, scaleD);
    fm_k3<<<NBLK,      256, 0, stream>>>(Gd, lsum, meanD, scaleD, bias, out);
}